// Round 1
// 67.842 us; speedup vs baseline: 1.0381x; 1.0381x over previous
//
#include <hip/hip_runtime.h>

#define NROW 4096      // 64*64 patch positions
#define NCOL 4225      // 65*65 plane
#define BATCH 8
#define MAGIC 0x13579BDFu

// ws layout: float partial[256]; unsigned flags[256];

// fast tanh for |x| <~ 4: tanh(x) = 1 - 2/(e^{2x}+1), e^{2x} via exp2
__device__ __forceinline__ float fast_tanh(float x) {
    float e = __builtin_exp2f(2.885390082f * x);   // 2*log2(e)*x
    return 1.0f - 2.0f / (e + 1.0f);
}

// 256 blocks x 1024 threads: 1 block/CU, 16 waves/CU (4 waves/SIMD -> latency hiding).
// Phase 3: one wave per softmax row (16 rows/block), float4 LDS reads, 64 exp/lane.
__global__ void __launch_bounds__(1024) k_fused(const float* __restrict__ x,
                                                const float* __restrict__ proj_w,
                                                const float* __restrict__ proj_b,
                                                float* __restrict__ out,
                                                float* __restrict__ partial,
                                                unsigned* __restrict__ flags) {
    __shared__ __align__(16) float cs_sh[NCOL];   // batch-summed plane
    __shared__ __align__(16) float s_sh[NROW];    // tanh scalars
    __shared__ float c_sh[16];                    // per-row softmax results
    const int tid = threadIdx.x;
    const int bid = blockIdx.x;

    // phase 1: colsum[p] = sum_b x[b,p]; 4 positions/thread + 129 tail
#pragma unroll
    for (int k = 0; k < 4; ++k) {
        int p = tid + (k << 10);
        float v = 0.0f;
#pragma unroll
        for (int b = 0; b < BATCH; ++b) v += x[b * NCOL + p];
        cs_sh[p] = v;
    }
    if (tid < NCOL - NROW) {       // 129-element tail
        int p = NROW + tid;
        float v = 0.0f;
#pragma unroll
        for (int b = 0; b < BATCH; ++b) v += x[b * NCOL + p];
        cs_sh[p] = v;
    }
    __syncthreads();

    // phase 2: s[n] = tanh(2x2 patch sum / 32) — 4 per thread, branch-free tanh
#pragma unroll
    for (int k = 0; k < 4; ++k) {
        int n = tid + (k << 10);
        int i = n >> 6, j = n & 63;
        const float* c = &cs_sh[i * 65 + j];
        s_sh[n] = fast_tanh((c[0] + c[1] + c[65] + c[66]) * (1.0f / 32.0f));
    }
    __syncthreads();

    // phase 3: wave w -> row bid*16+w. 64 lanes sweep all 4096 m via float4 LDS
    // reads (ds_read_b128, conflict-free: 64 lanes x 16B consecutive).
    const int wave = tid >> 6;
    const int lane = tid & 63;
    const int row = (bid << 4) + wave;
    const float t = 8.0f * 1.4426950408889634f * s_sh[row];  // fold log2(e)
    float num = 0.0f, den = 0.0f;
    const float4* s4 = (const float4*)s_sh;
#pragma unroll
    for (int k = 0; k < 16; ++k) {
        float4 sv = s4[lane + (k << 6)];
        float e0 = __builtin_exp2f(t * sv.x);  // |arg| < 11.6, no max-subtract
        float e1 = __builtin_exp2f(t * sv.y);
        float e2 = __builtin_exp2f(t * sv.z);
        float e3 = __builtin_exp2f(t * sv.w);
        num += e0 * sv.x;
        den += e0;
        num += e1 * sv.y;
        den += e1;
        num += e2 * sv.z;
        den += e2;
        num += e3 * sv.w;
        den += e3;
    }
#pragma unroll
    for (int off = 32; off; off >>= 1) {
        num += __shfl_down(num, off, 64);
        den += __shfl_down(den, off, 64);
    }
    if (lane == 0) c_sh[wave] = num / den;
    __syncthreads();

    // phase 4: publish block partial (atomic RMW -> device-coherent; no init needed)
    if (tid == 0) {
        float bs = 0.0f;
#pragma unroll
        for (int r = 0; r < 16; ++r) bs += c_sh[r];
        atomicExch(&partial[bid], bs);
        __threadfence();
        atomicExch(&flags[bid], MAGIC);
    }

    // phase 5: block 0, wave 0 waits for all partials and finalizes.
    // All other blocks retire unconditionally -> no deadlock under any scheduling.
    // s_sleep backoff keeps the poll from serializing against publishers' atomicExch.
    if (bid == 0 && tid < 64) {
        float pw = proj_w[tid];    // hoist: overlap load latency with the spin
        float pb = proj_b[0];
#pragma unroll
        for (int q = 0; q < 4; ++q) {
            int i = tid + (q << 6);
            while (atomicAdd(&flags[i], 0u) != MAGIC) __builtin_amdgcn_s_sleep(1);
        }
        __threadfence();
        float acc_c = 0.0f;
#pragma unroll
        for (int q = 0; q < 4; ++q) {
            int i = tid + (q << 6);
            acc_c += atomicAdd(&partial[i], 0.0f);  // coherent read, fixed order
        }
#pragma unroll
        for (int off = 32; off; off >>= 1) {
            acc_c += __shfl_down(acc_c, off, 64);
            pw    += __shfl_down(pw, off, 64);
        }
        if (tid == 0) {
            float o = (acc_c * (1.0f / (float)NROW)) * pw + pb;
#pragma unroll
            for (int b = 0; b < BATCH; ++b) out[b] = o;
        }
    }
}

extern "C" void kernel_launch(void* const* d_in, const int* in_sizes, int n_in,
                              void* d_out, int out_size, void* d_ws, size_t ws_size,
                              hipStream_t stream) {
    const float* x      = (const float*)d_in[0];
    const float* proj_w = (const float*)d_in[1];
    const float* proj_b = (const float*)d_in[2];
    float* out = (float*)d_out;

    float*    partial = (float*)d_ws;
    unsigned* flags   = (unsigned*)(partial + 256);

    k_fused<<<256, 1024, 0, stream>>>(x, proj_w, proj_b, out, partial, flags);
}

// Round 2
// 64.655 us; speedup vs baseline: 1.0893x; 1.0493x over previous
//
#include <hip/hip_runtime.h>

#define NROW 4096      // 64*64 patch positions
#define NCOL 4225      // 65*65 plane
#define BATCH 8

// ws layout: float partial[256];

// fast tanh for |x| <~ 4: tanh(x) = 1 - 2/(e^{2x}+1), e^{2x} via exp2
__device__ __forceinline__ float fast_tanh(float x) {
    float e = __builtin_exp2f(2.885390082f * x);   // 2*log2(e)*x
    return 1.0f - 2.0f / (e + 1.0f);
}

// Kernel 1: 256 blocks x 1024 threads (1 block/CU, 4 waves/SIMD).
// Computes block partial sums of softmax-row results; plain store, no protocol.
// Cross-block visibility is provided by the kernel boundary (runtime L2 flush),
// replacing 256 device-scope fences + an atomic-RMW spin loop.
__global__ void __launch_bounds__(1024) k_rows(const float* __restrict__ x,
                                               float* __restrict__ partial) {
    __shared__ __align__(16) float cs_sh[NCOL];   // batch-summed plane
    __shared__ __align__(16) float s_sh[NROW];    // tanh scalars
    __shared__ float c_sh[16];                    // per-row softmax results
    const int tid = threadIdx.x;
    const int bid = blockIdx.x;

    // phase 1: colsum[p] = sum_b x[b,p]; 4 positions/thread + 129 tail
#pragma unroll
    for (int k = 0; k < 4; ++k) {
        int p = tid + (k << 10);
        float v = 0.0f;
#pragma unroll
        for (int b = 0; b < BATCH; ++b) v += x[b * NCOL + p];
        cs_sh[p] = v;
    }
    if (tid < NCOL - NROW) {       // 129-element tail
        int p = NROW + tid;
        float v = 0.0f;
#pragma unroll
        for (int b = 0; b < BATCH; ++b) v += x[b * NCOL + p];
        cs_sh[p] = v;
    }
    __syncthreads();

    // phase 2: s[n] = tanh(2x2 patch sum / 32) — 4 per thread, branch-free tanh
#pragma unroll
    for (int k = 0; k < 4; ++k) {
        int n = tid + (k << 10);
        int i = n >> 6, j = n & 63;
        const float* c = &cs_sh[i * 65 + j];
        s_sh[n] = fast_tanh((c[0] + c[1] + c[65] + c[66]) * (1.0f / 32.0f));
    }
    __syncthreads();

    // phase 3: wave w -> row bid*16+w. 64 lanes sweep all 4096 m via float4 LDS
    // reads (ds_read_b128, conflict-free: 64 lanes x 16B consecutive).
    const int wave = tid >> 6;
    const int lane = tid & 63;
    const int row = (bid << 4) + wave;
    const float t = 8.0f * 1.4426950408889634f * s_sh[row];  // fold log2(e)
    float num = 0.0f, den = 0.0f;
    const float4* s4 = (const float4*)s_sh;
#pragma unroll
    for (int k = 0; k < 16; ++k) {
        float4 sv = s4[lane + (k << 6)];
        float e0 = __builtin_exp2f(t * sv.x);  // |arg| < 11.6, no max-subtract
        float e1 = __builtin_exp2f(t * sv.y);
        float e2 = __builtin_exp2f(t * sv.z);
        float e3 = __builtin_exp2f(t * sv.w);
        num += e0 * sv.x;
        den += e0;
        num += e1 * sv.y;
        den += e1;
        num += e2 * sv.z;
        den += e2;
        num += e3 * sv.w;
        den += e3;
    }
#pragma unroll
    for (int off = 32; off; off >>= 1) {
        num += __shfl_down(num, off, 64);
        den += __shfl_down(den, off, 64);
    }
    if (lane == 0) c_sh[wave] = num / den;
    __syncthreads();

    // publish block partial: plain store, no fence, no flags
    if (tid == 0) {
        float bs = 0.0f;
#pragma unroll
        for (int r = 0; r < 16; ++r) bs += c_sh[r];
        partial[bid] = bs;
    }
}

// Kernel 2: one wave finalizes. Same reduction order as before (q-loop then
// 64-lane shuffle tree) -> bit-identical numerics.
__global__ void __launch_bounds__(64) k_final(const float* __restrict__ partial,
                                              const float* __restrict__ proj_w,
                                              const float* __restrict__ proj_b,
                                              float* __restrict__ out) {
    const int lane = threadIdx.x;
    float acc = 0.0f;
#pragma unroll
    for (int q = 0; q < 4; ++q) acc += partial[lane + (q << 6)];
    float pw = proj_w[lane];
#pragma unroll
    for (int off = 32; off; off >>= 1) {
        acc += __shfl_down(acc, off, 64);
        pw  += __shfl_down(pw, off, 64);
    }
    if (lane == 0) {
        float o = (acc * (1.0f / (float)NROW)) * pw + proj_b[0];
#pragma unroll
        for (int b = 0; b < BATCH; ++b) out[b] = o;
    }
}

extern "C" void kernel_launch(void* const* d_in, const int* in_sizes, int n_in,
                              void* d_out, int out_size, void* d_ws, size_t ws_size,
                              hipStream_t stream) {
    const float* x      = (const float*)d_in[0];
    const float* proj_w = (const float*)d_in[1];
    const float* proj_b = (const float*)d_in[2];
    float* out = (float*)d_out;

    float* partial = (float*)d_ws;

    k_rows<<<256, 1024, 0, stream>>>(x, partial);
    k_final<<<1, 64, 0, stream>>>(partial, proj_w, proj_b, out);
}